// Round 2
// baseline (597.192 us; speedup 1.0000x reference)
//
#include <hip/hip_runtime.h>
#include <hip/hip_bf16.h>

typedef __bf16 bf16x8 __attribute__((ext_vector_type(8)));
typedef float f32x4 __attribute__((ext_vector_type(4)));
typedef unsigned short ushort_t;

#define S_LEN 4096
#define D_DIM 512
#define NBATCH 4

static __device__ __forceinline__ ushort_t f2bf(float f) {
    __hip_bfloat16 h = __float2bfloat16(f);
    return __builtin_bit_cast(ushort_t, h);
}

// ---------------- fp32 -> bf16 convert (with optional scale) ----------------
__global__ void cvt_bf16_kernel(const float* __restrict__ src, ushort_t* __restrict__ dst,
                                int n4, float scale) {
    int i = blockIdx.x * blockDim.x + threadIdx.x;
    if (i >= n4) return;
    float4 v = reinterpret_cast<const float4*>(src)[i];
    ushort4 o;
    o.x = f2bf(v.x * scale);
    o.y = f2bf(v.y * scale);
    o.z = f2bf(v.z * scale);
    o.w = f2bf(v.w * scale);
    reinterpret_cast<ushort4*>(dst)[i] = o;
}

// ---------------- generic bf16 GEMM: C[M][N] = A[M][K] * Bt[N][K]^T ----------------
__global__ __launch_bounds__(256) void gemm_bt(const ushort_t* __restrict__ A,
                                               const ushort_t* __restrict__ Bt,
                                               ushort_t* __restrict__ C,
                                               int M, int N, int K) {
    __shared__ ushort_t As[128 * 40];
    __shared__ ushort_t Bs[128 * 40];
    int tid = threadIdx.x;
    int w = tid >> 6, lane = tid & 63, c = lane & 15, g = lane >> 4;
    int m0 = blockIdx.x * 128, n0 = blockIdx.y * 128;
    int wm = (w >> 1) * 64, wn = (w & 1) * 64;

    f32x4 acc[4][4];
#pragma unroll
    for (int mi = 0; mi < 4; mi++)
#pragma unroll
        for (int ni = 0; ni < 4; ni++) acc[mi][ni] = (f32x4){0.f, 0.f, 0.f, 0.f};

    for (int k0 = 0; k0 < K; k0 += 32) {
        __syncthreads();
#pragma unroll
        for (int r = 0; r < 2; r++) {
            int cl = r * 256 + tid;
            int row = cl >> 2, cin = cl & 3;
            *(bf16x8*)(&As[row * 40 + cin * 8]) =
                *(const bf16x8*)(A + (size_t)(m0 + row) * K + k0 + cin * 8);
            *(bf16x8*)(&Bs[row * 40 + cin * 8]) =
                *(const bf16x8*)(Bt + (size_t)(n0 + row) * K + k0 + cin * 8);
        }
        __syncthreads();

        bf16x8 af[4], bfr[4];
#pragma unroll
        for (int i2 = 0; i2 < 4; i2++)
            af[i2] = *(const bf16x8*)(&As[(wm + i2 * 16 + c) * 40 + g * 8]);
#pragma unroll
        for (int i2 = 0; i2 < 4; i2++)
            bfr[i2] = *(const bf16x8*)(&Bs[(wn + i2 * 16 + c) * 40 + g * 8]);
#pragma unroll
        for (int mi = 0; mi < 4; mi++)
#pragma unroll
            for (int ni = 0; ni < 4; ni++)
                acc[mi][ni] = __builtin_amdgcn_mfma_f32_16x16x32_bf16(af[mi], bfr[ni],
                                                                      acc[mi][ni], 0, 0, 0);
    }

#pragma unroll
    for (int mi = 0; mi < 4; mi++)
#pragma unroll
        for (int ni = 0; ni < 4; ni++)
#pragma unroll
            for (int j = 0; j < 4; j++)
                C[(size_t)(m0 + wm + mi * 16 + g * 4 + j) * N + n0 + wn + ni * 16 + c] =
                    f2bf(acc[mi][ni][j]);
}

// ---------------- flash attention, causal, 8-wave WG with in-WG KV-split-2 ----------------
// WG = (batch, 64-row q-block). 512 threads = 2 teams x 4 waves x 16 q-rows.
// Team h processes KVBLK=32 tiles 2i+h (equal trip counts -> aligned barriers).
// Final merge of the two online-softmax states via LDS stash.
#define KVB 32
#define KPAD 520   // K tile row pad (ushorts)
#define VPAD 40    // V^T tile row pad (ushorts, 16B-aligned)
#define PPAD 40
#define LDS_K_BYTES (2 * KVB * KPAD * 2)       // 66560
#define LDS_V_BYTES (2 * D_DIM * VPAD * 2)     // 81920
#define LDS_P_BYTES (2 * 64 * PPAD * 2)        // 10240

__global__ __launch_bounds__(512, 2) void attn_kernel(const ushort_t* __restrict__ Q,
                                                      const ushort_t* __restrict__ K,
                                                      const ushort_t* __restrict__ Vt,
                                                      float* __restrict__ out) {
    __shared__ __align__(16) char ldsbuf[LDS_K_BYTES + LDS_V_BYTES + LDS_P_BYTES];

    const int i = blockIdx.x;
    const int b = i & 3;          // consecutive blocks -> different XCDs, batch-major per XCD
    const int j = i >> 2;         // q-block 0..63
    const int tid = threadIdx.x;
    const int w = tid >> 6, lane = tid & 63, c = lane & 15, g = lane >> 4;
    const int team = w >> 2, wt = w & 3;
    const int ttid = tid & 255;

    ushort_t* Ks = (ushort_t*)(ldsbuf) + team * (KVB * KPAD);
    ushort_t* Vs = (ushort_t*)(ldsbuf + LDS_K_BYTES) + team * (D_DIM * VPAD);
    ushort_t* Ps = (ushort_t*)(ldsbuf + LDS_K_BYTES + LDS_V_BYTES) + team * (64 * PPAD);
    ushort_t* pw = Ps + wt * 16 * PPAD;

    const int qbase = j * 64;
    const int sbase = b * S_LEN;

    // Q fragments (1/sqrt(512) folded into W_q); both teams load the same 64 rows.
    bf16x8 qf[16];
    {
        const ushort_t* qrow = Q + (size_t)(sbase + qbase + wt * 16 + c) * D_DIM;
#pragma unroll
        for (int kk = 0; kk < 16; kk++)
            qf[kk] = *(const bf16x8*)(qrow + kk * 32 + g * 8);
    }

    f32x4 o[32];
#pragma unroll
    for (int t = 0; t < 32; t++) o[t] = (f32x4){0.f, 0.f, 0.f, 0.f};
    float m_r[4], l_r[4];
#pragma unroll
    for (int jj = 0; jj < 4; jj++) { m_r[jj] = -1e30f; l_r[jj] = 0.f; }

    for (int t = 0; t <= j; ++t) {
        const int kv0 = (2 * t + team) * KVB;
        __syncthreads();
        // ---- stage K tile [32][512] and V^T tile [512][32] into this team's set ----
        {
            const ushort_t* kg = K + (size_t)(sbase + kv0) * D_DIM;
#pragma unroll
            for (int r = 0; r < 8; r++) {
                int cl = r * 256 + ttid;
                int row = cl >> 6, cin = cl & 63;
                *(bf16x8*)(&Ks[row * KPAD + cin * 8]) =
                    *(const bf16x8*)(kg + row * D_DIM + cin * 8);
            }
            const ushort_t* vg = Vt + (size_t)sbase + kv0;
#pragma unroll
            for (int r = 0; r < 8; r++) {
                int cl = r * 256 + ttid;
                int row = cl >> 2, cin = cl & 3;
                *(bf16x8*)(&Vs[row * VPAD + cin * 8]) =
                    *(const bf16x8*)(vg + (size_t)row * (NBATCH * S_LEN) + cin * 8);
            }
        }
        __syncthreads();

        // ---- QK^T : S[16 q][32 kv] per wave ----
        f32x4 s4[2];
#pragma unroll
        for (int nt = 0; nt < 2; nt++) {
            f32x4 acc = (f32x4){0.f, 0.f, 0.f, 0.f};
#pragma unroll
            for (int kk = 0; kk < 16; kk++) {
                bf16x8 kf = *(const bf16x8*)(&Ks[(nt * 16 + c) * KPAD + kk * 32 + g * 8]);
                acc = __builtin_amdgcn_mfma_f32_16x16x32_bf16(qf[kk], kf, acc, 0, 0, 0);
            }
            s4[nt] = acc;
        }

        // ---- causal mask (only the diagonal pair of tiles, t == j) ----
        if (t == j) {
#pragma unroll
            for (int nt = 0; nt < 2; nt++)
#pragma unroll
                for (int jj = 0; jj < 4; jj++) {
                    int qrow = qbase + wt * 16 + g * 4 + jj;
                    int kvcol = kv0 + nt * 16 + c;
                    if (kvcol > qrow) s4[nt][jj] = -1e38f;
                }
        }

        // ---- online softmax (m floored at -1e30 so fully-masked tiles contribute 0) ----
        float mx[4];
#pragma unroll
        for (int jj = 0; jj < 4; jj++) {
            float v = fmaxf(s4[0][jj], s4[1][jj]);
#pragma unroll
            for (int off = 1; off < 16; off <<= 1) v = fmaxf(v, __shfl_xor(v, off, 64));
            mx[jj] = v;
        }
        float alpha[4], rs[4];
#pragma unroll
        for (int jj = 0; jj < 4; jj++) {
            float mn = fmaxf(m_r[jj], mx[jj]);
            alpha[jj] = __expf(m_r[jj] - mn);
            m_r[jj] = mn;
            rs[jj] = 0.f;
        }
#pragma unroll
        for (int nt = 0; nt < 2; nt++)
#pragma unroll
            for (int jj = 0; jj < 4; jj++) {
                float p = __expf(s4[nt][jj] - m_r[jj]);
                rs[jj] += p;
                pw[(g * 4 + jj) * PPAD + nt * 16 + c] = f2bf(p);
            }
#pragma unroll
        for (int jj = 0; jj < 4; jj++) {
            float v = rs[jj];
#pragma unroll
            for (int off = 1; off < 16; off <<= 1) v += __shfl_xor(v, off, 64);
            l_r[jj] = l_r[jj] * alpha[jj] + v;
        }
#pragma unroll
        for (int dt = 0; dt < 32; dt++)
#pragma unroll
            for (int jj = 0; jj < 4; jj++) o[dt][jj] *= alpha[jj];

        // ---- PV : O += P[16x32] * V[32x512] ----
        bf16x8 pf = *(const bf16x8*)(&pw[c * PPAD + g * 8]);
#pragma unroll
        for (int dt = 0; dt < 32; dt++) {
            bf16x8 vf = *(const bf16x8*)(&Vs[(dt * 16 + c) * VPAD + g * 8]);
            o[dt] = __builtin_amdgcn_mfma_f32_16x16x32_bf16(pf, vf, o[dt], 0, 0, 0);
        }
    }

    // ---- merge the two teams' states via LDS stash, then store ----
    __syncthreads();
    float* stO = (float*)ldsbuf;                       // [64][520] fp32
    float* stML = (float*)(ldsbuf + 64 * 520 * 4);     // [64][2]
    if (team == 1) {
        if (c == 0) {
#pragma unroll
            for (int jj = 0; jj < 4; jj++) {
                int r = wt * 16 + g * 4 + jj;
                stML[r * 2 + 0] = m_r[jj];
                stML[r * 2 + 1] = l_r[jj];
            }
        }
#pragma unroll
        for (int dt = 0; dt < 32; dt++)
#pragma unroll
            for (int jj = 0; jj < 4; jj++)
                stO[(wt * 16 + g * 4 + jj) * 520 + dt * 16 + c] = o[dt][jj];
    }
    __syncthreads();
    if (team == 0) {
        float a0[4], a1[4], inv[4];
#pragma unroll
        for (int jj = 0; jj < 4; jj++) {
            int r = wt * 16 + g * 4 + jj;
            float m1 = stML[r * 2 + 0], l1 = stML[r * 2 + 1];
            float mm = fmaxf(m_r[jj], m1);
            a0[jj] = __expf(m_r[jj] - mm);
            a1[jj] = __expf(m1 - mm);
            float l = l_r[jj] * a0[jj] + l1 * a1[jj];
            inv[jj] = 1.f / l;
        }
#pragma unroll
        for (int dt = 0; dt < 32; dt++)
#pragma unroll
            for (int jj = 0; jj < 4; jj++) {
                int r = wt * 16 + g * 4 + jj;
                out[(size_t)(sbase + qbase + r) * D_DIM + dt * 16 + c] =
                    (o[dt][jj] * a0[jj] + stO[r * 520 + dt * 16 + c] * a1[jj]) * inv[jj];
            }
    }
}

// ---------------- host launch ----------------
extern "C" void kernel_launch(void* const* d_in, const int* in_sizes, int n_in,
                              void* d_out, int out_size, void* d_ws, size_t ws_size,
                              hipStream_t stream) {
    const float* X  = (const float*)d_in[0];
    const float* Wq = (const float*)d_in[1];
    const float* Wk = (const float*)d_in[2];
    const float* Wv = (const float*)d_in[3];
    float* out = (float*)d_out;

    const int M = NBATCH * S_LEN;   // 16384
    const int Kd = D_DIM;           // 512
    const size_t XBF_BYTES = (size_t)M * Kd * 2;
    const size_t W_BYTES   = (size_t)Kd * Kd * 2;

    char* p = (char*)d_ws;
    ushort_t* Xbf = (ushort_t*)p;              p += XBF_BYTES;
    ushort_t* Wqb = (ushort_t*)p;              p += W_BYTES;
    ushort_t* Wkb = (ushort_t*)p;              p += W_BYTES;
    ushort_t* Wvb = (ushort_t*)p;              p += W_BYTES;
    ushort_t* Qb  = (ushort_t*)p;              p += XBF_BYTES;
    ushort_t* Kb  = (ushort_t*)p;              p += XBF_BYTES;
    ushort_t* Vtb = (ushort_t*)p;              p += XBF_BYTES;

    const float qscale = 0.044194173824159216f;  // 1/sqrt(512)

    {
        int n4 = (M * Kd) / 4;
        cvt_bf16_kernel<<<(n4 + 255) / 256, 256, 0, stream>>>(X, Xbf, n4, 1.0f);
        int w4 = (Kd * Kd) / 4;
        cvt_bf16_kernel<<<(w4 + 255) / 256, 256, 0, stream>>>(Wq, Wqb, w4, qscale);
        cvt_bf16_kernel<<<(w4 + 255) / 256, 256, 0, stream>>>(Wk, Wkb, w4, 1.0f);
        cvt_bf16_kernel<<<(w4 + 255) / 256, 256, 0, stream>>>(Wv, Wvb, w4, 1.0f);
    }
    gemm_bt<<<dim3(M / 128, Kd / 128), 256, 0, stream>>>(Xbf, Wqb, Qb, M, Kd, Kd);
    gemm_bt<<<dim3(M / 128, Kd / 128), 256, 0, stream>>>(Xbf, Wkb, Kb, M, Kd, Kd);
    gemm_bt<<<dim3(Kd / 128, M / 128), 256, 0, stream>>>(Wvb, Xbf, Vtb, Kd, M, Kd);
    attn_kernel<<<256, 512, 0, stream>>>(Qb, Kb, Vtb, out);
}

// Round 3
// 569.241 us; speedup vs baseline: 1.0491x; 1.0491x over previous
//
#include <hip/hip_runtime.h>
#include <hip/hip_bf16.h>

typedef __bf16 bf16x8 __attribute__((ext_vector_type(8)));
typedef float f32x4 __attribute__((ext_vector_type(4)));
typedef unsigned short ushort_t;

#define S_LEN 4096
#define D_DIM 512
#define NBATCH 4
#define NROW (NBATCH * S_LEN)

static __device__ __forceinline__ ushort_t f2bf(float f) {
    __hip_bfloat16 h = __float2bfloat16(f);
    return __builtin_bit_cast(ushort_t, h);
}

// ---------------- fp32 -> bf16 convert (with optional scale) ----------------
__global__ void cvt_bf16_kernel(const float* __restrict__ src, ushort_t* __restrict__ dst,
                                int n4, float scale) {
    int i = blockIdx.x * blockDim.x + threadIdx.x;
    if (i >= n4) return;
    float4 v = reinterpret_cast<const float4*>(src)[i];
    ushort4 o;
    o.x = f2bf(v.x * scale);
    o.y = f2bf(v.y * scale);
    o.z = f2bf(v.z * scale);
    o.w = f2bf(v.w * scale);
    reinterpret_cast<ushort4*>(dst)[i] = o;
}

// ---------------- generic bf16 GEMM: C[M][N] = A[M][K] * Bt[N][K]^T ----------------
__global__ __launch_bounds__(256) void gemm_bt(const ushort_t* __restrict__ A,
                                               const ushort_t* __restrict__ Bt,
                                               ushort_t* __restrict__ C,
                                               int M, int N, int K) {
    __shared__ ushort_t As[128 * 40];
    __shared__ ushort_t Bs[128 * 40];
    int tid = threadIdx.x;
    int w = tid >> 6, lane = tid & 63, c = lane & 15, g = lane >> 4;
    int m0 = blockIdx.x * 128, n0 = blockIdx.y * 128;
    int wm = (w >> 1) * 64, wn = (w & 1) * 64;

    f32x4 acc[4][4];
#pragma unroll
    for (int mi = 0; mi < 4; mi++)
#pragma unroll
        for (int ni = 0; ni < 4; ni++) acc[mi][ni] = (f32x4){0.f, 0.f, 0.f, 0.f};

    for (int k0 = 0; k0 < K; k0 += 32) {
        __syncthreads();
#pragma unroll
        for (int r = 0; r < 2; r++) {
            int cl = r * 256 + tid;
            int row = cl >> 2, cin = cl & 3;
            *(bf16x8*)(&As[row * 40 + cin * 8]) =
                *(const bf16x8*)(A + (size_t)(m0 + row) * K + k0 + cin * 8);
            *(bf16x8*)(&Bs[row * 40 + cin * 8]) =
                *(const bf16x8*)(Bt + (size_t)(n0 + row) * K + k0 + cin * 8);
        }
        __syncthreads();

        bf16x8 af[4], bfr[4];
#pragma unroll
        for (int i2 = 0; i2 < 4; i2++)
            af[i2] = *(const bf16x8*)(&As[(wm + i2 * 16 + c) * 40 + g * 8]);
#pragma unroll
        for (int i2 = 0; i2 < 4; i2++)
            bfr[i2] = *(const bf16x8*)(&Bs[(wn + i2 * 16 + c) * 40 + g * 8]);
#pragma unroll
        for (int mi = 0; mi < 4; mi++)
#pragma unroll
            for (int ni = 0; ni < 4; ni++)
                acc[mi][ni] = __builtin_amdgcn_mfma_f32_16x16x32_bf16(af[mi], bfr[ni],
                                                                      acc[mi][ni], 0, 0, 0);
    }

#pragma unroll
    for (int mi = 0; mi < 4; mi++)
#pragma unroll
        for (int ni = 0; ni < 4; ni++)
#pragma unroll
            for (int j = 0; j < 4; j++)
                C[(size_t)(m0 + wm + mi * 16 + g * 4 + j) * N + n0 + wn + ni * 16 + c] =
                    f2bf(acc[mi][ni][j]);
}

// ------------- flash attention partials: KV-split-2, 4 waves, KVB=32 -------------
// 512 WGs: WG (b, j, h) covers q-rows [64j,64j+64), kv half-tiles kv0=(2t+h)*32, t=0..j.
// Writes RAW partial O (h=0 -> d_out, h=1 -> part1) + per-row (m,l). Merge kernel combines.
// LDS 79.4 KB -> 2 WGs/CU co-resident; VGPR ~252 -> 2 waves/SIMD. No spills.
#define KVB 32
#define KPAD 520   // K tile row pad (ushorts)
#define VPAD 40    // V^T tile row pad (ushorts, 16B-aligned)
#define PPAD 40

__global__ __launch_bounds__(256, 2) void attn_part_kernel(const ushort_t* __restrict__ Q,
                                                           const ushort_t* __restrict__ K,
                                                           const ushort_t* __restrict__ Vt,
                                                           float* __restrict__ out0,
                                                           float* __restrict__ out1,
                                                           float* __restrict__ ml) {
    __shared__ ushort_t Ks[KVB * KPAD];     // 33280 B
    __shared__ ushort_t Vs[D_DIM * VPAD];   // 40960 B
    __shared__ ushort_t Ps[4 * 16 * PPAD];  //  5120 B

    const int gid = blockIdx.x;
    const int j = 63 - (gid >> 3);      // largest-j WGs dispatch first (balance)
    const int b = (gid >> 1) & 3;
    const int h = gid & 1;
    const int tid = threadIdx.x;
    const int w = tid >> 6, lane = tid & 63, c = lane & 15, g = lane >> 4;

    const int qbase = j * 64;
    const int sbase = b * S_LEN;
    ushort_t* pw = Ps + w * 16 * PPAD;

    // Q fragments (1/sqrt(512) folded into W_q)
    bf16x8 qf[16];
    {
        const ushort_t* qrow = Q + (size_t)(sbase + qbase + w * 16 + c) * D_DIM;
#pragma unroll
        for (int kk = 0; kk < 16; kk++)
            qf[kk] = *(const bf16x8*)(qrow + kk * 32 + g * 8);
    }

    f32x4 o[32];
#pragma unroll
    for (int t = 0; t < 32; t++) o[t] = (f32x4){0.f, 0.f, 0.f, 0.f};
    float m_r[4], l_r[4];
#pragma unroll
    for (int jj = 0; jj < 4; jj++) { m_r[jj] = -1e30f; l_r[jj] = 0.f; }

    for (int t = 0; t <= j; ++t) {
        const int kv0 = (2 * t + h) * KVB;
        __syncthreads();
        // ---- stage K tile [32][512] and V^T tile [512][32] ----
        {
            const ushort_t* kg = K + (size_t)(sbase + kv0) * D_DIM;
#pragma unroll
            for (int r = 0; r < 8; r++) {
                int cl = r * 256 + tid;
                int row = cl >> 6, cin = cl & 63;
                *(bf16x8*)(&Ks[row * KPAD + cin * 8]) =
                    *(const bf16x8*)(kg + row * D_DIM + cin * 8);
            }
            const ushort_t* vg = Vt + (size_t)sbase + kv0;
#pragma unroll
            for (int r = 0; r < 8; r++) {
                int cl = r * 256 + tid;
                int row = cl >> 2, cin = cl & 3;
                *(bf16x8*)(&Vs[row * VPAD + cin * 8]) =
                    *(const bf16x8*)(vg + (size_t)row * NROW + cin * 8);
            }
        }
        __syncthreads();

        // ---- QK^T : S[16 q][32 kv] per wave ----
        f32x4 s4[2];
#pragma unroll
        for (int nt = 0; nt < 2; nt++) {
            f32x4 acc = (f32x4){0.f, 0.f, 0.f, 0.f};
#pragma unroll
            for (int kk = 0; kk < 16; kk++) {
                bf16x8 kf = *(const bf16x8*)(&Ks[(nt * 16 + c) * KPAD + kk * 32 + g * 8]);
                acc = __builtin_amdgcn_mfma_f32_16x16x32_bf16(qf[kk], kf, acc, 0, 0, 0);
            }
            s4[nt] = acc;
        }

        // ---- causal mask (diagonal 64-block, t == j) ----
        if (t == j) {
#pragma unroll
            for (int nt = 0; nt < 2; nt++)
#pragma unroll
                for (int jj = 0; jj < 4; jj++) {
                    int qrow = qbase + w * 16 + g * 4 + jj;
                    int kvcol = kv0 + nt * 16 + c;
                    if (kvcol > qrow) s4[nt][jj] = -1e38f;
                }
        }

        // ---- online softmax (m floored at -1e30: fully-masked rows contribute l=0) ----
        float mx[4];
#pragma unroll
        for (int jj = 0; jj < 4; jj++) {
            float v = fmaxf(s4[0][jj], s4[1][jj]);
#pragma unroll
            for (int off = 1; off < 16; off <<= 1) v = fmaxf(v, __shfl_xor(v, off, 64));
            mx[jj] = v;
        }
        float alpha[4], rs[4];
#pragma unroll
        for (int jj = 0; jj < 4; jj++) {
            float mn = fmaxf(m_r[jj], mx[jj]);
            alpha[jj] = __expf(m_r[jj] - mn);
            m_r[jj] = mn;
            rs[jj] = 0.f;
        }
#pragma unroll
        for (int nt = 0; nt < 2; nt++)
#pragma unroll
            for (int jj = 0; jj < 4; jj++) {
                float p = __expf(s4[nt][jj] - m_r[jj]);
                rs[jj] += p;
                pw[(g * 4 + jj) * PPAD + nt * 16 + c] = f2bf(p);
            }
#pragma unroll
        for (int jj = 0; jj < 4; jj++) {
            float v = rs[jj];
#pragma unroll
            for (int off = 1; off < 16; off <<= 1) v += __shfl_xor(v, off, 64);
            l_r[jj] = l_r[jj] * alpha[jj] + v;
        }
#pragma unroll
        for (int dt = 0; dt < 32; dt++)
#pragma unroll
            for (int jj = 0; jj < 4; jj++) o[dt][jj] *= alpha[jj];

        // ---- PV : O += P[16x32] * V[32x512] ----
        bf16x8 pf = *(const bf16x8*)(&pw[c * PPAD + g * 8]);
#pragma unroll
        for (int dt = 0; dt < 32; dt++) {
            bf16x8 vf = *(const bf16x8*)(&Vs[(dt * 16 + c) * VPAD + g * 8]);
            o[dt] = __builtin_amdgcn_mfma_f32_16x16x32_bf16(pf, vf, o[dt], 0, 0, 0);
        }
    }

    // ---- write raw partial + (m,l) ----
    float* po = h ? out1 : out0;
#pragma unroll
    for (int dt = 0; dt < 32; dt++)
#pragma unroll
        for (int jj = 0; jj < 4; jj++)
            po[(size_t)(sbase + qbase + w * 16 + g * 4 + jj) * D_DIM + dt * 16 + c] =
                o[dt][jj];
    if (c == 0) {
#pragma unroll
        for (int jj = 0; jj < 4; jj++) {
            int r = sbase + qbase + w * 16 + g * 4 + jj;
            ml[((size_t)h * NROW + r) * 2 + 0] = m_r[jj];
            ml[((size_t)h * NROW + r) * 2 + 1] = l_r[jj];
        }
    }
}

// ---------------- merge the two KV-split partials ----------------
__global__ __launch_bounds__(256) void attn_merge_kernel(float* __restrict__ out,
                                                         const float* __restrict__ part1,
                                                         const float* __restrict__ ml) {
    int i = blockIdx.x * blockDim.x + threadIdx.x;   // float4 index
    int row = i >> 7;                                 // 128 float4 per row
    float m0 = ml[(size_t)row * 2 + 0], l0 = ml[(size_t)row * 2 + 1];
    float m1 = ml[((size_t)NROW + row) * 2 + 0], l1 = ml[((size_t)NROW + row) * 2 + 1];
    float mm = fmaxf(m0, m1);
    float a0 = __expf(m0 - mm), a1 = __expf(m1 - mm);
    float inv = 1.f / (l0 * a0 + l1 * a1);
    float4 x0 = reinterpret_cast<float4*>(out)[i];
    float4 x1 = reinterpret_cast<const float4*>(part1)[i];
    float4 r;
    r.x = (x0.x * a0 + x1.x * a1) * inv;
    r.y = (x0.y * a0 + x1.y * a1) * inv;
    r.z = (x0.z * a0 + x1.z * a1) * inv;
    r.w = (x0.w * a0 + x1.w * a1) * inv;
    reinterpret_cast<float4*>(out)[i] = r;
}

// ---------------- host launch ----------------
extern "C" void kernel_launch(void* const* d_in, const int* in_sizes, int n_in,
                              void* d_out, int out_size, void* d_ws, size_t ws_size,
                              hipStream_t stream) {
    const float* X  = (const float*)d_in[0];
    const float* Wq = (const float*)d_in[1];
    const float* Wk = (const float*)d_in[2];
    const float* Wv = (const float*)d_in[3];
    float* out = (float*)d_out;

    const int M = NROW;             // 16384
    const int Kd = D_DIM;           // 512
    const size_t XBF_BYTES = (size_t)M * Kd * 2;
    const size_t W_BYTES   = (size_t)Kd * Kd * 2;

    char* p = (char*)d_ws;
    ushort_t* Xbf = (ushort_t*)p;              p += XBF_BYTES;
    ushort_t* Wqb = (ushort_t*)p;              p += W_BYTES;
    ushort_t* Wkb = (ushort_t*)p;              p += W_BYTES;
    ushort_t* Wvb = (ushort_t*)p;              p += W_BYTES;
    ushort_t* Qb  = (ushort_t*)p;              p += XBF_BYTES;
    ushort_t* Kb  = (ushort_t*)p;              p += XBF_BYTES;
    ushort_t* Vtb = (ushort_t*)p;              p += XBF_BYTES;
    float*    part1 = (float*)p;               p += (size_t)M * Kd * 4;  // 32 MB
    float*    ml    = (float*)p;               p += (size_t)2 * M * 2 * 4;

    const float qscale = 0.044194173824159216f;  // 1/sqrt(512)

    {
        int n4 = (M * Kd) / 4;
        cvt_bf16_kernel<<<(n4 + 255) / 256, 256, 0, stream>>>(X, Xbf, n4, 1.0f);
        int w4 = (Kd * Kd) / 4;
        cvt_bf16_kernel<<<(w4 + 255) / 256, 256, 0, stream>>>(Wq, Wqb, w4, qscale);
        cvt_bf16_kernel<<<(w4 + 255) / 256, 256, 0, stream>>>(Wk, Wkb, w4, 1.0f);
        cvt_bf16_kernel<<<(w4 + 255) / 256, 256, 0, stream>>>(Wv, Wvb, w4, 1.0f);
    }
    gemm_bt<<<dim3(M / 128, Kd / 128), 256, 0, stream>>>(Xbf, Wqb, Qb, M, Kd, Kd);
    gemm_bt<<<dim3(M / 128, Kd / 128), 256, 0, stream>>>(Xbf, Wkb, Kb, M, Kd, Kd);
    gemm_bt<<<dim3(Kd / 128, M / 128), 256, 0, stream>>>(Wvb, Xbf, Vtb, Kd, M, Kd);

    attn_part_kernel<<<512, 256, 0, stream>>>(Qb, Kb, Vtb, out, part1, ml);
    attn_merge_kernel<<<(M * Kd / 4) / 256, 256, 0, stream>>>(out, part1, ml);
}

// Round 4
// 343.692 us; speedup vs baseline: 1.7376x; 1.6563x over previous
//
#include <hip/hip_runtime.h>
#include <hip/hip_bf16.h>

typedef __bf16 bf16x8 __attribute__((ext_vector_type(8)));
typedef float f32x4 __attribute__((ext_vector_type(4)));
typedef unsigned short ushort_t;

#define S_LEN 4096
#define D_DIM 512
#define NBATCH 4
#define NROW (NBATCH * S_LEN)

static __device__ __forceinline__ ushort_t f2bf(float f) {
    __hip_bfloat16 h = __float2bfloat16(f);
    return __builtin_bit_cast(ushort_t, h);
}

// ---------------- fp32 -> bf16 convert (with optional scale) ----------------
__global__ void cvt_bf16_kernel(const float* __restrict__ src, ushort_t* __restrict__ dst,
                                int n4, float scale) {
    int i = blockIdx.x * blockDim.x + threadIdx.x;
    if (i >= n4) return;
    float4 v = reinterpret_cast<const float4*>(src)[i];
    ushort4 o;
    o.x = f2bf(v.x * scale);
    o.y = f2bf(v.y * scale);
    o.z = f2bf(v.z * scale);
    o.w = f2bf(v.w * scale);
    reinterpret_cast<ushort4*>(dst)[i] = o;
}

// ---------------- generic bf16 GEMM: C[M][N] = A[M][K] * Bt[N][K]^T ----------------
__global__ __launch_bounds__(256) void gemm_bt(const ushort_t* __restrict__ A,
                                               const ushort_t* __restrict__ Bt,
                                               ushort_t* __restrict__ C,
                                               int M, int N, int K) {
    __shared__ ushort_t As[128 * 40];
    __shared__ ushort_t Bs[128 * 40];
    int tid = threadIdx.x;
    int w = tid >> 6, lane = tid & 63, c = lane & 15, g = lane >> 4;
    int m0 = blockIdx.x * 128, n0 = blockIdx.y * 128;
    int wm = (w >> 1) * 64, wn = (w & 1) * 64;

    f32x4 acc[4][4];
#pragma unroll
    for (int mi = 0; mi < 4; mi++)
#pragma unroll
        for (int ni = 0; ni < 4; ni++) acc[mi][ni] = (f32x4){0.f, 0.f, 0.f, 0.f};

    for (int k0 = 0; k0 < K; k0 += 32) {
        __syncthreads();
#pragma unroll
        for (int r = 0; r < 2; r++) {
            int cl = r * 256 + tid;
            int row = cl >> 2, cin = cl & 3;
            *(bf16x8*)(&As[row * 40 + cin * 8]) =
                *(const bf16x8*)(A + (size_t)(m0 + row) * K + k0 + cin * 8);
            *(bf16x8*)(&Bs[row * 40 + cin * 8]) =
                *(const bf16x8*)(Bt + (size_t)(n0 + row) * K + k0 + cin * 8);
        }
        __syncthreads();

        bf16x8 af[4], bfr[4];
#pragma unroll
        for (int i2 = 0; i2 < 4; i2++)
            af[i2] = *(const bf16x8*)(&As[(wm + i2 * 16 + c) * 40 + g * 8]);
#pragma unroll
        for (int i2 = 0; i2 < 4; i2++)
            bfr[i2] = *(const bf16x8*)(&Bs[(wn + i2 * 16 + c) * 40 + g * 8]);
#pragma unroll
        for (int mi = 0; mi < 4; mi++)
#pragma unroll
            for (int ni = 0; ni < 4; ni++)
                acc[mi][ni] = __builtin_amdgcn_mfma_f32_16x16x32_bf16(af[mi], bfr[ni],
                                                                      acc[mi][ni], 0, 0, 0);
    }

#pragma unroll
    for (int mi = 0; mi < 4; mi++)
#pragma unroll
        for (int ni = 0; ni < 4; ni++)
#pragma unroll
            for (int j = 0; j < 4; j++)
                C[(size_t)(m0 + wm + mi * 16 + g * 4 + j) * N + n0 + wn + ni * 16 + c] =
                    f2bf(acc[mi][ni][j]);
}

// ------------- flash attention partials: 8-wave D-split, paired q-blocks -------------
// 256 WGs of 512 threads. WG (b, p, h): processes q-blocks j=p then j=63-p (64 rows each),
// kv tiles t<=j with t%2==h (KVB=64). Waves = (row-group r 0..3, D-half d 0..1):
// QK^T computed redundantly per d-pair (o state halves to 64 regs -> 2 waves/SIMD, no spill).
// Work per WG = 32 or 33 tiles (exact balance). Raw partials merged by attn_merge_kernel.
#define KVB 64
#define KPAD 520   // K tile row pad (ushorts)
#define VPAD 72    // V^T tile row pad (ushorts)
#define PPAD 72

__global__ __launch_bounds__(512, 2) void attn_part_kernel(const ushort_t* __restrict__ Q,
                                                           const ushort_t* __restrict__ K,
                                                           const ushort_t* __restrict__ Vt,
                                                           float* __restrict__ out0,
                                                           float* __restrict__ out1,
                                                           float* __restrict__ ml) {
    __shared__ ushort_t Ks[KVB * KPAD];       // 66560 B
    __shared__ ushort_t Vs[D_DIM * VPAD];     // 73728 B
    __shared__ ushort_t Ps[4 * 16 * PPAD];    //  9216 B  -> 149504 total

    const int gid = blockIdx.x;
    const int b = gid & 3;
    const int h = (gid >> 2) & 1;
    const int p = gid >> 3;            // 0..31
    const int tid = threadIdx.x;
    const int w = tid >> 6, lane = tid & 63, c = lane & 15, g = lane >> 4;
    const int r = w & 3, d = w >> 2;   // row-group, D-half

    const int sbase = b * S_LEN;
    ushort_t* pw = Ps + r * 16 * PPAD;
    float* po = h ? out1 : out0;

    for (int phase = 0; phase < 2; ++phase) {
        const int jblk = phase ? (63 - p) : p;
        const int qbase = jblk * 64;

        // Q fragments for this q-block (1/sqrt(512) folded into W_q)
        bf16x8 qf[16];
        {
            const ushort_t* qrow = Q + (size_t)(sbase + qbase + r * 16 + c) * D_DIM;
#pragma unroll
            for (int kk = 0; kk < 16; kk++)
                qf[kk] = *(const bf16x8*)(qrow + kk * 32 + g * 8);
        }

        f32x4 o[16];
#pragma unroll
        for (int t = 0; t < 16; t++) o[t] = (f32x4){0.f, 0.f, 0.f, 0.f};
        float m_r[4], l_r[4];
#pragma unroll
        for (int jj = 0; jj < 4; jj++) { m_r[jj] = -1e30f; l_r[jj] = 0.f; }

        for (int t = h; t <= jblk; t += 2) {
            const int kv0 = t * KVB;
            __syncthreads();
            // ---- stage K tile [64][512] and V^T tile [512][64] (512 threads) ----
            {
                const ushort_t* kg = K + (size_t)(sbase + kv0) * D_DIM;
#pragma unroll
                for (int rr = 0; rr < 8; rr++) {
                    int cl = rr * 512 + tid;          // 4096 chunks
                    int row = cl >> 6, cin = cl & 63;
                    *(bf16x8*)(&Ks[row * KPAD + cin * 8]) =
                        *(const bf16x8*)(kg + row * D_DIM + cin * 8);
                }
                const ushort_t* vg = Vt + (size_t)sbase + kv0;
#pragma unroll
                for (int rr = 0; rr < 8; rr++) {
                    int cl = rr * 512 + tid;
                    int row = cl >> 3, cin = cl & 7;  // 8 chunks per Vt row
                    *(bf16x8*)(&Vs[row * VPAD + cin * 8]) =
                        *(const bf16x8*)(vg + (size_t)row * NROW + cin * 8);
                }
            }
            __syncthreads();

            // ---- QK^T : S[16 q][64 kv] (redundant across d-pair) ----
            f32x4 s4[4];
#pragma unroll
            for (int nt = 0; nt < 4; nt++) {
                f32x4 acc = (f32x4){0.f, 0.f, 0.f, 0.f};
#pragma unroll
                for (int kk = 0; kk < 16; kk++) {
                    bf16x8 kf = *(const bf16x8*)(&Ks[(nt * 16 + c) * KPAD + kk * 32 + g * 8]);
                    acc = __builtin_amdgcn_mfma_f32_16x16x32_bf16(qf[kk], kf, acc, 0, 0, 0);
                }
                s4[nt] = acc;
            }

            // ---- causal mask (diagonal tile only; that tile has t==jblk) ----
            if (t == jblk) {
#pragma unroll
                for (int nt = 0; nt < 4; nt++)
#pragma unroll
                    for (int jj = 0; jj < 4; jj++) {
                        int qrow = qbase + r * 16 + g * 4 + jj;
                        int kvcol = kv0 + nt * 16 + c;
                        if (kvcol > qrow) s4[nt][jj] = -1e38f;
                    }
            }

            // ---- online softmax (per-wave; m floored at -1e30) ----
            float mx[4];
#pragma unroll
            for (int jj = 0; jj < 4; jj++) {
                float v = fmaxf(fmaxf(s4[0][jj], s4[1][jj]), fmaxf(s4[2][jj], s4[3][jj]));
#pragma unroll
                for (int off = 1; off < 16; off <<= 1) v = fmaxf(v, __shfl_xor(v, off, 64));
                mx[jj] = v;
            }
            float alpha[4], rs[4];
#pragma unroll
            for (int jj = 0; jj < 4; jj++) {
                float mn = fmaxf(m_r[jj], mx[jj]);
                alpha[jj] = __expf(m_r[jj] - mn);
                m_r[jj] = mn;
                rs[jj] = 0.f;
            }
#pragma unroll
            for (int nt = 0; nt < 4; nt++)
#pragma unroll
                for (int jj = 0; jj < 4; jj++) {
                    float pv = __expf(s4[nt][jj] - m_r[jj]);
                    rs[jj] += pv;
                    pw[(g * 4 + jj) * PPAD + nt * 16 + c] = f2bf(pv);
                }
#pragma unroll
            for (int jj = 0; jj < 4; jj++) {
                float v = rs[jj];
#pragma unroll
                for (int off = 1; off < 16; off <<= 1) v += __shfl_xor(v, off, 64);
                l_r[jj] = l_r[jj] * alpha[jj] + v;
            }
#pragma unroll
            for (int dt = 0; dt < 16; dt++)
#pragma unroll
                for (int jj = 0; jj < 4; jj++) o[dt][jj] *= alpha[jj];

            // ---- PV : O[16 rows][256 cols (d-half)] += P[16x64] * V[64x256] ----
            bf16x8 pf[2];
#pragma unroll
            for (int kk = 0; kk < 2; kk++)
                pf[kk] = *(const bf16x8*)(&pw[c * PPAD + kk * 32 + g * 8]);
#pragma unroll
            for (int dt = 0; dt < 16; dt++) {
                f32x4 acc = o[dt];
#pragma unroll
                for (int kk = 0; kk < 2; kk++) {
                    bf16x8 vf = *(const bf16x8*)(&Vs[(d * 256 + dt * 16 + c) * VPAD + kk * 32 + g * 8]);
                    acc = __builtin_amdgcn_mfma_f32_16x16x32_bf16(pf[kk], vf, acc, 0, 0, 0);
                }
                o[dt] = acc;
            }
        }

        // ---- write raw partial + (m,l) for this q-block ----
#pragma unroll
        for (int dt = 0; dt < 16; dt++)
#pragma unroll
            for (int jj = 0; jj < 4; jj++)
                po[(size_t)(sbase + qbase + r * 16 + g * 4 + jj) * D_DIM +
                   d * 256 + dt * 16 + c] = o[dt][jj];
        if (d == 0 && c == 0) {
#pragma unroll
            for (int jj = 0; jj < 4; jj++) {
                int row = sbase + qbase + r * 16 + g * 4 + jj;
                ml[((size_t)h * NROW + row) * 2 + 0] = m_r[jj];
                ml[((size_t)h * NROW + row) * 2 + 1] = l_r[jj];
            }
        }
    }
}

// ---------------- merge the two h-split partials ----------------
__global__ __launch_bounds__(256) void attn_merge_kernel(float* __restrict__ out,
                                                         const float* __restrict__ part1,
                                                         const float* __restrict__ ml) {
    int i = blockIdx.x * blockDim.x + threadIdx.x;   // float4 index
    int row = i >> 7;                                 // 128 float4 per row
    float m0 = ml[(size_t)row * 2 + 0], l0 = ml[(size_t)row * 2 + 1];
    float m1 = ml[((size_t)NROW + row) * 2 + 0], l1 = ml[((size_t)NROW + row) * 2 + 1];
    float mm = fmaxf(m0, m1);
    float a0 = __expf(m0 - mm), a1 = __expf(m1 - mm);
    float inv = 1.f / (l0 * a0 + l1 * a1);
    float4 x0 = reinterpret_cast<float4*>(out)[i];
    float4 x1 = reinterpret_cast<const float4*>(part1)[i];
    float4 r;
    r.x = (x0.x * a0 + x1.x * a1) * inv;
    r.y = (x0.y * a0 + x1.y * a1) * inv;
    r.z = (x0.z * a0 + x1.z * a1) * inv;
    r.w = (x0.w * a0 + x1.w * a1) * inv;
    reinterpret_cast<float4*>(out)[i] = r;
}

// ---------------- host launch ----------------
extern "C" void kernel_launch(void* const* d_in, const int* in_sizes, int n_in,
                              void* d_out, int out_size, void* d_ws, size_t ws_size,
                              hipStream_t stream) {
    const float* X  = (const float*)d_in[0];
    const float* Wq = (const float*)d_in[1];
    const float* Wk = (const float*)d_in[2];
    const float* Wv = (const float*)d_in[3];
    float* out = (float*)d_out;

    const int M = NROW;             // 16384
    const int Kd = D_DIM;           // 512
    const size_t XBF_BYTES = (size_t)M * Kd * 2;
    const size_t W_BYTES   = (size_t)Kd * Kd * 2;

    char* p = (char*)d_ws;
    ushort_t* Xbf = (ushort_t*)p;              p += XBF_BYTES;
    ushort_t* Wqb = (ushort_t*)p;              p += W_BYTES;
    ushort_t* Wkb = (ushort_t*)p;              p += W_BYTES;
    ushort_t* Wvb = (ushort_t*)p;              p += W_BYTES;
    ushort_t* Qb  = (ushort_t*)p;              p += XBF_BYTES;
    ushort_t* Kb  = (ushort_t*)p;              p += XBF_BYTES;
    ushort_t* Vtb = (ushort_t*)p;              p += XBF_BYTES;
    float*    part1 = (float*)p;               p += (size_t)M * Kd * 4;  // 32 MB
    float*    ml    = (float*)p;               p += (size_t)2 * M * 2 * 4;

    const float qscale = 0.044194173824159216f;  // 1/sqrt(512)

    {
        int n4 = (M * Kd) / 4;
        cvt_bf16_kernel<<<(n4 + 255) / 256, 256, 0, stream>>>(X, Xbf, n4, 1.0f);
        int w4 = (Kd * Kd) / 4;
        cvt_bf16_kernel<<<(w4 + 255) / 256, 256, 0, stream>>>(Wq, Wqb, w4, qscale);
        cvt_bf16_kernel<<<(w4 + 255) / 256, 256, 0, stream>>>(Wk, Wkb, w4, 1.0f);
        cvt_bf16_kernel<<<(w4 + 255) / 256, 256, 0, stream>>>(Wv, Wvb, w4, 1.0f);
    }
    gemm_bt<<<dim3(M / 128, Kd / 128), 256, 0, stream>>>(Xbf, Wqb, Qb, M, Kd, Kd);
    gemm_bt<<<dim3(M / 128, Kd / 128), 256, 0, stream>>>(Xbf, Wkb, Kb, M, Kd, Kd);
    gemm_bt<<<dim3(Kd / 128, M / 128), 256, 0, stream>>>(Wvb, Xbf, Vtb, Kd, M, Kd);

    attn_part_kernel<<<256, 512, 0, stream>>>(Qb, Kb, Vtb, out, part1, ml);
    attn_merge_kernel<<<(M * Kd / 4) / 256, 256, 0, stream>>>(out, part1, ml);
}

// Round 5
// 330.714 us; speedup vs baseline: 1.8058x; 1.0392x over previous
//
#include <hip/hip_runtime.h>
#include <hip/hip_bf16.h>

typedef __bf16 bf16x8 __attribute__((ext_vector_type(8)));
typedef float f32x4 __attribute__((ext_vector_type(4)));
typedef unsigned short ushort_t;

#define S_LEN 4096
#define D_DIM 512
#define NBATCH 4
#define NROW (NBATCH * S_LEN)

static __device__ __forceinline__ ushort_t f2bf(float f) {
    __hip_bfloat16 h = __float2bfloat16(f);
    return __builtin_bit_cast(ushort_t, h);
}

// ---------------- fp32 -> bf16 convert (with optional scale) ----------------
__global__ void cvt_bf16_kernel(const float* __restrict__ src, ushort_t* __restrict__ dst,
                                int n4, float scale) {
    int i = blockIdx.x * blockDim.x + threadIdx.x;
    if (i >= n4) return;
    float4 v = reinterpret_cast<const float4*>(src)[i];
    ushort4 o;
    o.x = f2bf(v.x * scale);
    o.y = f2bf(v.y * scale);
    o.z = f2bf(v.z * scale);
    o.w = f2bf(v.w * scale);
    reinterpret_cast<ushort4*>(dst)[i] = o;
}

// ---------------- generic bf16 GEMM: C[M][N] = A[M][K] * Bt[N][K]^T ----------------
__global__ __launch_bounds__(256) void gemm_bt(const ushort_t* __restrict__ A,
                                               const ushort_t* __restrict__ Bt,
                                               ushort_t* __restrict__ C,
                                               int M, int N, int K) {
    __shared__ ushort_t As[128 * 40];
    __shared__ ushort_t Bs[128 * 40];
    int tid = threadIdx.x;
    int w = tid >> 6, lane = tid & 63, c = lane & 15, g = lane >> 4;
    int m0 = blockIdx.x * 128, n0 = blockIdx.y * 128;
    int wm = (w >> 1) * 64, wn = (w & 1) * 64;

    f32x4 acc[4][4];
#pragma unroll
    for (int mi = 0; mi < 4; mi++)
#pragma unroll
        for (int ni = 0; ni < 4; ni++) acc[mi][ni] = (f32x4){0.f, 0.f, 0.f, 0.f};

    for (int k0 = 0; k0 < K; k0 += 32) {
        __syncthreads();
#pragma unroll
        for (int r = 0; r < 2; r++) {
            int cl = r * 256 + tid;
            int row = cl >> 2, cin = cl & 3;
            *(bf16x8*)(&As[row * 40 + cin * 8]) =
                *(const bf16x8*)(A + (size_t)(m0 + row) * K + k0 + cin * 8);
            *(bf16x8*)(&Bs[row * 40 + cin * 8]) =
                *(const bf16x8*)(Bt + (size_t)(n0 + row) * K + k0 + cin * 8);
        }
        __syncthreads();

        bf16x8 af[4], bfr[4];
#pragma unroll
        for (int i2 = 0; i2 < 4; i2++)
            af[i2] = *(const bf16x8*)(&As[(wm + i2 * 16 + c) * 40 + g * 8]);
#pragma unroll
        for (int i2 = 0; i2 < 4; i2++)
            bfr[i2] = *(const bf16x8*)(&Bs[(wn + i2 * 16 + c) * 40 + g * 8]);
#pragma unroll
        for (int mi = 0; mi < 4; mi++)
#pragma unroll
            for (int ni = 0; ni < 4; ni++)
                acc[mi][ni] = __builtin_amdgcn_mfma_f32_16x16x32_bf16(af[mi], bfr[ni],
                                                                      acc[mi][ni], 0, 0, 0);
    }

#pragma unroll
    for (int mi = 0; mi < 4; mi++)
#pragma unroll
        for (int ni = 0; ni < 4; ni++)
#pragma unroll
            for (int j = 0; j < 4; j++)
                C[(size_t)(m0 + wm + mi * 16 + g * 4 + j) * N + n0 + wn + ni * 16 + c] =
                    f2bf(acc[mi][ni][j]);
}

// ------------- flash attention partials: wave-specialized QK, D-split PV -------------
// 256 WGs of 512 threads. WG (b, p, h): q-blocks j=p then 63-p; kv tiles t%2==h (KVB=64).
// Waves = (row-group r 0..3, role d 0..1). Staging: d0->K, d1->V.
// QK+softmax+P-write: d0 ONLY (no redundancy). PV: all 8 waves, D-half each.
// alpha passed d0->d1 via small LDS array; wave-uniform skip of o-rescale when alpha==1.
#define KVB 64
#define KPAD 520   // K tile row pad (ushorts)
#define VPAD 72    // V^T tile row pad (ushorts)
#define PPAD 72

__global__ __launch_bounds__(512, 2) void attn_part_kernel(const ushort_t* __restrict__ Q,
                                                           const ushort_t* __restrict__ K,
                                                           const ushort_t* __restrict__ Vt,
                                                           float* __restrict__ out0,
                                                           float* __restrict__ out1,
                                                           float* __restrict__ ml) {
    __shared__ ushort_t Ks[KVB * KPAD];       // 66560 B
    __shared__ ushort_t Vs[D_DIM * VPAD];     // 73728 B
    __shared__ ushort_t Ps[4 * 16 * PPAD];    //  9216 B
    __shared__ float alphaS[64];              //   256 B

    const int gid = blockIdx.x;
    const int b = gid & 3;
    const int h = (gid >> 2) & 1;
    const int p = gid >> 3;            // 0..31
    const int tid = threadIdx.x;
    const int ttid = tid & 255;
    const int w = tid >> 6, lane = tid & 63, c = lane & 15, g = lane >> 4;
    const int r = w & 3, d = w >> 2;   // row-group, role/D-half

    const int sbase = b * S_LEN;
    ushort_t* pw = Ps + r * 16 * PPAD;
    float* po = h ? out1 : out0;

    for (int phase = 0; phase < 2; ++phase) {
        const int jblk = phase ? (63 - p) : p;
        const int qbase = jblk * 64;

        // Q fragments only needed by QK waves (d==0)
        bf16x8 qf[16];
        if (d == 0) {
            const ushort_t* qrow = Q + (size_t)(sbase + qbase + r * 16 + c) * D_DIM;
#pragma unroll
            for (int kk = 0; kk < 16; kk++)
                qf[kk] = *(const bf16x8*)(qrow + kk * 32 + g * 8);
        }

        f32x4 o[16];
#pragma unroll
        for (int t = 0; t < 16; t++) o[t] = (f32x4){0.f, 0.f, 0.f, 0.f};
        float m_r[4], l_r[4];
#pragma unroll
        for (int jj = 0; jj < 4; jj++) { m_r[jj] = -1e30f; l_r[jj] = 0.f; }

        for (int t = h; t <= jblk; t += 2) {
            const int kv0 = t * KVB;
            __syncthreads();
            // ---- stage: d0 waves -> K tile [64][512]; d1 waves -> V^T tile [512][64] ----
            if (d == 0) {
                const ushort_t* kg = K + (size_t)(sbase + kv0) * D_DIM;
#pragma unroll
                for (int rr = 0; rr < 16; rr++) {
                    int cl = rr * 256 + ttid;
                    int row = cl >> 6, cin = cl & 63;
                    *(bf16x8*)(&Ks[row * KPAD + cin * 8]) =
                        *(const bf16x8*)(kg + row * D_DIM + cin * 8);
                }
            } else {
                const ushort_t* vg = Vt + (size_t)sbase + kv0;
#pragma unroll
                for (int rr = 0; rr < 16; rr++) {
                    int cl = rr * 256 + ttid;
                    int row = cl >> 3, cin = cl & 7;
                    *(bf16x8*)(&Vs[row * VPAD + cin * 8]) =
                        *(const bf16x8*)(vg + (size_t)row * NROW + cin * 8);
                }
            }
            __syncthreads();

            float alpha[4];
            if (d == 0) {
                // ---- QK^T : S[16 q][64 kv], d0 only ----
                f32x4 s4[4];
#pragma unroll
                for (int nt = 0; nt < 4; nt++) {
                    f32x4 acc = (f32x4){0.f, 0.f, 0.f, 0.f};
#pragma unroll
                    for (int kk = 0; kk < 16; kk++) {
                        bf16x8 kf = *(const bf16x8*)(&Ks[(nt * 16 + c) * KPAD + kk * 32 + g * 8]);
                        acc = __builtin_amdgcn_mfma_f32_16x16x32_bf16(qf[kk], kf, acc, 0, 0, 0);
                    }
                    s4[nt] = acc;
                }

                // ---- causal mask (diagonal tile only) ----
                if (t == jblk) {
#pragma unroll
                    for (int nt = 0; nt < 4; nt++)
#pragma unroll
                        for (int jj = 0; jj < 4; jj++) {
                            int qrow = qbase + r * 16 + g * 4 + jj;
                            int kvcol = kv0 + nt * 16 + c;
                            if (kvcol > qrow) s4[nt][jj] = -1e38f;
                        }
                }

                // ---- online softmax ----
                float mx[4];
#pragma unroll
                for (int jj = 0; jj < 4; jj++) {
                    float v = fmaxf(fmaxf(s4[0][jj], s4[1][jj]), fmaxf(s4[2][jj], s4[3][jj]));
#pragma unroll
                    for (int off = 1; off < 16; off <<= 1) v = fmaxf(v, __shfl_xor(v, off, 64));
                    mx[jj] = v;
                }
                float rs[4];
#pragma unroll
                for (int jj = 0; jj < 4; jj++) {
                    float mn = fmaxf(m_r[jj], mx[jj]);
                    alpha[jj] = __expf(m_r[jj] - mn);   // == 1.0f exactly when max unchanged
                    m_r[jj] = mn;
                    rs[jj] = 0.f;
                }
#pragma unroll
                for (int nt = 0; nt < 4; nt++)
#pragma unroll
                    for (int jj = 0; jj < 4; jj++) {
                        float pv = __expf(s4[nt][jj] - m_r[jj]);
                        rs[jj] += pv;
                        pw[(g * 4 + jj) * PPAD + nt * 16 + c] = f2bf(pv);
                    }
#pragma unroll
                for (int jj = 0; jj < 4; jj++) {
                    float v = rs[jj];
#pragma unroll
                    for (int off = 1; off < 16; off <<= 1) v += __shfl_xor(v, off, 64);
                    l_r[jj] = l_r[jj] * alpha[jj] + v;
                }
                if (c == 0) {
#pragma unroll
                    for (int jj = 0; jj < 4; jj++) alphaS[r * 16 + g * 4 + jj] = alpha[jj];
                }
            }
            __syncthreads();

            if (d == 1) {
#pragma unroll
                for (int jj = 0; jj < 4; jj++) alpha[jj] = alphaS[r * 16 + g * 4 + jj];
            }

            // ---- rescale O (skipped wave-uniformly when all alphas == 1) ----
            bool need = !(alpha[0] == 1.f && alpha[1] == 1.f && alpha[2] == 1.f && alpha[3] == 1.f);
            if (__any((int)need)) {
#pragma unroll
                for (int dt = 0; dt < 16; dt++)
#pragma unroll
                    for (int jj = 0; jj < 4; jj++) o[dt][jj] *= alpha[jj];
            }

            // ---- PV : O[16 rows][256 cols (d-half)] += P[16x64] * V[64x256] ----
            bf16x8 pf[2];
#pragma unroll
            for (int kk = 0; kk < 2; kk++)
                pf[kk] = *(const bf16x8*)(&pw[c * PPAD + kk * 32 + g * 8]);
#pragma unroll
            for (int dt = 0; dt < 16; dt++) {
                f32x4 acc = o[dt];
#pragma unroll
                for (int kk = 0; kk < 2; kk++) {
                    bf16x8 vf = *(const bf16x8*)(&Vs[(d * 256 + dt * 16 + c) * VPAD + kk * 32 + g * 8]);
                    acc = __builtin_amdgcn_mfma_f32_16x16x32_bf16(pf[kk], vf, acc, 0, 0, 0);
                }
                o[dt] = acc;
            }
        }

        // ---- write raw partial + (m,l) for this q-block ----
#pragma unroll
        for (int dt = 0; dt < 16; dt++)
#pragma unroll
            for (int jj = 0; jj < 4; jj++)
                po[(size_t)(sbase + qbase + r * 16 + g * 4 + jj) * D_DIM +
                   d * 256 + dt * 16 + c] = o[dt][jj];
        if (d == 0 && c == 0) {
#pragma unroll
            for (int jj = 0; jj < 4; jj++) {
                int row = sbase + qbase + r * 16 + g * 4 + jj;
                ml[((size_t)h * NROW + row) * 2 + 0] = m_r[jj];
                ml[((size_t)h * NROW + row) * 2 + 1] = l_r[jj];
            }
        }
    }
}

// ---------------- merge the two h-split partials ----------------
__global__ __launch_bounds__(256) void attn_merge_kernel(float* __restrict__ out,
                                                         const float* __restrict__ part1,
                                                         const float* __restrict__ ml) {
    int i = blockIdx.x * blockDim.x + threadIdx.x;   // float4 index
    int row = i >> 7;                                 // 128 float4 per row
    float m0 = ml[(size_t)row * 2 + 0], l0 = ml[(size_t)row * 2 + 1];
    float m1 = ml[((size_t)NROW + row) * 2 + 0], l1 = ml[((size_t)NROW + row) * 2 + 1];
    float mm = fmaxf(m0, m1);
    float a0 = __expf(m0 - mm), a1 = __expf(m1 - mm);
    float inv = 1.f / (l0 * a0 + l1 * a1);
    float4 x0 = reinterpret_cast<float4*>(out)[i];
    float4 x1 = reinterpret_cast<const float4*>(part1)[i];
    float4 r;
    r.x = (x0.x * a0 + x1.x * a1) * inv;
    r.y = (x0.y * a0 + x1.y * a1) * inv;
    r.z = (x0.z * a0 + x1.z * a1) * inv;
    r.w = (x0.w * a0 + x1.w * a1) * inv;
    reinterpret_cast<float4*>(out)[i] = r;
}

// ---------------- host launch ----------------
extern "C" void kernel_launch(void* const* d_in, const int* in_sizes, int n_in,
                              void* d_out, int out_size, void* d_ws, size_t ws_size,
                              hipStream_t stream) {
    const float* X  = (const float*)d_in[0];
    const float* Wq = (const float*)d_in[1];
    const float* Wk = (const float*)d_in[2];
    const float* Wv = (const float*)d_in[3];
    float* out = (float*)d_out;

    const int M = NROW;             // 16384
    const int Kd = D_DIM;           // 512
    const size_t XBF_BYTES = (size_t)M * Kd * 2;
    const size_t W_BYTES   = (size_t)Kd * Kd * 2;

    char* p = (char*)d_ws;
    ushort_t* Xbf = (ushort_t*)p;              p += XBF_BYTES;
    ushort_t* Wqb = (ushort_t*)p;              p += W_BYTES;
    ushort_t* Wkb = (ushort_t*)p;              p += W_BYTES;
    ushort_t* Wvb = (ushort_t*)p;              p += W_BYTES;
    ushort_t* Qb  = (ushort_t*)p;              p += XBF_BYTES;
    ushort_t* Kb  = (ushort_t*)p;              p += XBF_BYTES;
    ushort_t* Vtb = (ushort_t*)p;              p += XBF_BYTES;
    float*    part1 = (float*)p;               p += (size_t)M * Kd * 4;  // 32 MB
    float*    ml    = (float*)p;               p += (size_t)2 * M * 2 * 4;

    const float qscale = 0.044194173824159216f;  // 1/sqrt(512)

    {
        int n4 = (M * Kd) / 4;
        cvt_bf16_kernel<<<(n4 + 255) / 256, 256, 0, stream>>>(X, Xbf, n4, 1.0f);
        int w4 = (Kd * Kd) / 4;
        cvt_bf16_kernel<<<(w4 + 255) / 256, 256, 0, stream>>>(Wq, Wqb, w4, qscale);
        cvt_bf16_kernel<<<(w4 + 255) / 256, 256, 0, stream>>>(Wk, Wkb, w4, 1.0f);
        cvt_bf16_kernel<<<(w4 + 255) / 256, 256, 0, stream>>>(Wv, Wvb, w4, 1.0f);
    }
    gemm_bt<<<dim3(M / 128, Kd / 128), 256, 0, stream>>>(Xbf, Wqb, Qb, M, Kd, Kd);
    gemm_bt<<<dim3(M / 128, Kd / 128), 256, 0, stream>>>(Xbf, Wkb, Kb, M, Kd, Kd);
    gemm_bt<<<dim3(Kd / 128, M / 128), 256, 0, stream>>>(Wvb, Xbf, Vtb, Kd, M, Kd);

    attn_part_kernel<<<256, 512, 0, stream>>>(Qb, Kb, Vtb, out, part1, ml);
    attn_merge_kernel<<<(M * Kd / 4) / 256, 256, 0, stream>>>(out, part1, ml);
}